// Round 4
// baseline (292.469 us; speedup 1.0000x reference)
//
#include <hip/hip_runtime.h>

#define N1 1000000
#define N2 131072
#define N3 16384
#define N4 2048
#define N5 256
#define C 48
#define NROWS (N2 + N3 + N4 + N5)   // 149,504 table rows total

// ---------------------------------------------------------------- zero ws
__global__ void zero_kernel(float4* __restrict__ p, int n4) {
    int i = blockIdx.x * blockDim.x + threadIdx.x;
    int stride = gridDim.x * blockDim.x;
    for (; i < n4; i += stride) p[i] = make_float4(0.f, 0.f, 0.f, 0.f);
}

// ------------------------------------------------- scatter-add (levels 3/4)
__global__ void scatter_add_kernel(const float* __restrict__ src,
                                   const int* __restrict__ parent,
                                   float* __restrict__ dst, int nrows) {
    int total = nrows * C;
    int stride = gridDim.x * blockDim.x;
    for (int e = blockIdx.x * blockDim.x + threadIdx.x; e < total; e += stride) {
        unsigned ue = (unsigned)e;
        unsigned r = ue / C;
        unsigned c = ue - r * C;
        atomicAdd(&dst[(unsigned)parent[r] * C + c], src[e]);
    }
}

// ---------------------------------------------------------- counting sort
__global__ void hist_kernel(const int* __restrict__ parent,
                            int* __restrict__ cnt, int n) {
    int i = blockIdx.x * blockDim.x + threadIdx.x;
    int stride = gridDim.x * blockDim.x;
    for (; i < n; i += stride) atomicAdd(&cnt[parent[i]], 1);
}

// per-256-chunk exclusive scan + chunk sums
__global__ void scan_block_kernel(const int* __restrict__ cnt,
                                  int* __restrict__ excl,
                                  int* __restrict__ bsum, int n) {
    __shared__ int lds[256];
    int tid = threadIdx.x;
    int g = blockIdx.x * 256 + tid;
    int v = (g < n) ? cnt[g] : 0;
    lds[tid] = v;
    __syncthreads();
    for (int off = 1; off < 256; off <<= 1) {
        int t = (tid >= off) ? lds[tid - off] : 0;
        __syncthreads();
        lds[tid] += t;
        __syncthreads();
    }
    if (g < n) excl[g] = lds[tid] - v;
    if (tid == 255) bsum[blockIdx.x] = lds[255];
}

// single-block exclusive scan of up to 512 chunk sums (in place)
__global__ void scan_top_kernel(int* __restrict__ bsum, int nb) {
    __shared__ int lds[512];
    int tid = threadIdx.x;
    int v = (tid < nb) ? bsum[tid] : 0;
    lds[tid] = v;
    __syncthreads();
    for (int off = 1; off < 512; off <<= 1) {
        int t = (tid >= off) ? lds[tid - off] : 0;
        __syncthreads();
        lds[tid] += t;
        __syncthreads();
    }
    if (tid < nb) bsum[tid] = lds[tid] - v;
}

// add chunk offset; write final exclusive offsets + a mutable cursor copy
__global__ void scan_fix_kernel(int* __restrict__ excl, const int* __restrict__ bsum,
                                int* __restrict__ cursor, int n) {
    int g = blockIdx.x * 256 + threadIdx.x;
    if (g >= n) return;
    int o = excl[g] + bsum[blockIdx.x];
    excl[g] = o;
    cursor[g] = o;
}

__global__ void reorder_kernel(const int* __restrict__ parent,
                               int* __restrict__ cursor,
                               int* __restrict__ rowid, int n) {
    int i = blockIdx.x * blockDim.x + threadIdx.x;
    int stride = gridDim.x * blockDim.x;
    for (; i < n; i += stride) {
        int r = parent[i];
        int p = atomicAdd(&cursor[r], 1);
        rowid[p] = i;
    }
}

// ---------------------------------------------- gather-style segment sum
// One 64-lane wave per segment; lanes 0..47 own one channel each.
// 2-wide unroll so two independent row loads are in flight per iteration.
__global__ void segsum_kernel(const float* __restrict__ src,
                              const int* __restrict__ rowid,
                              const int* __restrict__ offs,
                              const int* __restrict__ cnt,
                              float* __restrict__ dst, int nseg) {
    int wid = threadIdx.x >> 6;
    int lane = threadIdx.x & 63;
    int seg = blockIdx.x * (blockDim.x >> 6) + wid;
    if (seg >= nseg) return;
    int start = offs[seg];
    int end = start + cnt[seg];
    float acc0 = 0.f, acc1 = 0.f;
    int k = start;
    for (; k + 1 < end; k += 2) {
        int r0 = rowid[k];
        int r1 = rowid[k + 1];
        float v0 = (lane < C) ? src[(size_t)r0 * C + lane] : 0.f;
        float v1 = (lane < C) ? src[(size_t)r1 * C + lane] : 0.f;
        acc0 += v0;
        acc1 += v1;
    }
    if (k < end) {
        int r0 = rowid[k];
        if (lane < C) acc0 += src[(size_t)r0 * C + lane];
    }
    if (lane < C) dst[(size_t)seg * C + lane] = acc0 + acc1;
}

// ------------------------------------------------------- per-row argmax
__device__ __forceinline__ int argmax48(const float4* __restrict__ row) {
    float best = -__builtin_inff();
    int bi = 0;
#pragma unroll
    for (int i = 0; i < 12; ++i) {
        float4 v = row[i];
        if (v.x > best) { best = v.x; bi = 4 * i + 0; }
        if (v.y > best) { best = v.y; bi = 4 * i + 1; }
        if (v.z > best) { best = v.z; bi = 4 * i + 2; }
        if (v.w > best) { best = v.w; bi = 4 * i + 3; }
    }
    return bi;
}

__global__ void row_argmax_kernel(const float4* __restrict__ tables,
                                  unsigned char* __restrict__ tab) {
    int r = blockIdx.x * blockDim.x + threadIdx.x;
    if (r >= NROWS) return;
    tab[r] = (unsigned char)argmax48(tables + (unsigned)r * 12u);
}

__global__ void final_gather_kernel(const unsigned char* __restrict__ tab2,
                                    const unsigned char* __restrict__ tab3,
                                    const unsigned char* __restrict__ tab4,
                                    const unsigned char* __restrict__ tab5,
                                    const int* __restrict__ idx2,
                                    const int* __restrict__ idx3,
                                    const int* __restrict__ idx4,
                                    const int* __restrict__ idx5,
                                    int* __restrict__ out) {
    int p = blockIdx.x * blockDim.x + threadIdx.x;
    if (p >= N1) return;
    out[0 * N1 + p] = (int)tab2[idx2[p]];
    out[1 * N1 + p] = (int)tab3[idx3[p]];
    out[2 * N1 + p] = (int)tab4[idx4[p]];
    out[3 * N1 + p] = (int)tab5[idx5[p]];
}

extern "C" void kernel_launch(void* const* d_in, const int* in_sizes, int n_in,
                              void* d_out, int out_size, void* d_ws, size_t ws_size,
                              hipStream_t stream) {
    const float* slabel  = (const float*)d_in[0];
    const int* parent2   = (const int*)d_in[1];
    const int* parent3   = (const int*)d_in[2];
    const int* parent4   = (const int*)d_in[3];
    const int* parent5   = (const int*)d_in[4];
    const int* idx2      = (const int*)d_in[5];
    const int* idx3      = (const int*)d_in[6];
    const int* idx4      = (const int*)d_in[7];
    const int* idx5      = (const int*)d_in[8];
    int* out = (int*)d_out;   // JAX argmax output dtype is int32

    // ---- workspace layout (dwords) ----
    // [f2|f3|f4|f5|tab|cnt2|cnt3]  <- zeroed each call
    // [offs2|cur2|rowid2|offs3|cur3|rowid3|bsum]
    float* f2 = (float*)d_ws;
    float* f3 = f2 + (size_t)N2 * C;
    float* f4 = f3 + (size_t)N3 * C;
    float* f5 = f4 + (size_t)N4 * C;
    unsigned char* tab = (unsigned char*)(f5 + (size_t)N5 * C);
    unsigned char* tab2 = tab;
    unsigned char* tab3 = tab2 + N2;
    unsigned char* tab4 = tab3 + N3;
    unsigned char* tab5 = tab4 + N4;
    int* cnt2  = (int*)(tab + NROWS);          // NROWS = 149,504 bytes = 37,376 dwords
    int* cnt3  = cnt2 + N2;
    int* offs2 = cnt3 + N3;                    // end of zeroed region
    int* cur2  = offs2 + N2;
    int* rowid2 = cur2 + N2;
    int* offs3 = rowid2 + N1;
    int* cur3  = offs3 + N3;
    int* rowid3 = cur3 + N3;
    int* bsum  = rowid3 + N2;                  // 512 ints, reused by both levels

    // zero region: tables + tab + cnt2 + cnt3
    const int zero_dwords = NROWS * C + NROWS / 4 + N2 + N3;  // 7,373,312
    const int zero_f4 = zero_dwords / 4;

    const int BLK = 256;

    // 1) zero accumulators + histograms (ws is poisoned between calls)
    zero_kernel<<<2048, BLK, 0, stream>>>((float4*)d_ws, zero_f4);

    // 2) level 1: counting-sort + gather segment-sum  (slabel -> f2)
    hist_kernel<<<2048, BLK, 0, stream>>>(parent2, cnt2, N1);
    scan_block_kernel<<<N2 / 256, 256, 0, stream>>>(cnt2, offs2, bsum, N2);
    scan_top_kernel<<<1, 512, 0, stream>>>(bsum, N2 / 256);
    scan_fix_kernel<<<N2 / 256, 256, 0, stream>>>(offs2, bsum, cur2, N2);
    reorder_kernel<<<2048, BLK, 0, stream>>>(parent2, cur2, rowid2, N1);
    segsum_kernel<<<N2 / 4, BLK, 0, stream>>>(slabel, rowid2, offs2, cnt2, f2, N2);

    // 3) level 2: same treatment  (f2 -> f3); f2 is L3-resident
    hist_kernel<<<512, BLK, 0, stream>>>(parent3, cnt3, N2);
    scan_block_kernel<<<N3 / 256, 256, 0, stream>>>(cnt3, offs3, bsum, N3);
    scan_top_kernel<<<1, 512, 0, stream>>>(bsum, N3 / 256);
    scan_fix_kernel<<<N3 / 256, 256, 0, stream>>>(offs3, bsum, cur3, N3);
    reorder_kernel<<<512, BLK, 0, stream>>>(parent3, cur3, rowid3, N2);
    segsum_kernel<<<N3 / 4, BLK, 0, stream>>>(f2, rowid3, offs3, cnt3, f3, N3);

    // 4) levels 3/4: tiny — plain atomics  (f3 -> f4 -> f5)
    scatter_add_kernel<<<512, BLK, 0, stream>>>(f3, parent4, f4, N3);
    scatter_add_kernel<<<128, BLK, 0, stream>>>(f4, parent5, f5, N4);

    // 5) per-row argmax over all four tables (contiguous)
    row_argmax_kernel<<<(NROWS + BLK - 1) / BLK, BLK, 0, stream>>>(
        (const float4*)d_ws, tab);

    // 6) per-point gather of precomputed argmax
    final_gather_kernel<<<(N1 + BLK - 1) / BLK, BLK, 0, stream>>>(
        tab2, tab3, tab4, tab5, idx2, idx3, idx4, idx5, out);
}

// Round 5
// 247.130 us; speedup vs baseline: 1.1835x; 1.1835x over previous
//
#include <hip/hip_runtime.h>

#define N1 1000000
#define N2 131072
#define N3 16384
#define N4 2048
#define N5 256
#define C 48
#define NROWS (N2 + N3 + N4 + N5)   // 149,504 table rows total

// ---------------------------------------------------------------- zero ws
__global__ void zero_kernel(float4* __restrict__ p, int n4) {
    int i = blockIdx.x * blockDim.x + threadIdx.x;
    int stride = gridDim.x * blockDim.x;
    for (; i < n4; i += stride) p[i] = make_float4(0.f, 0.f, 0.f, 0.f);
}

// ------------------------------------------- scatter-add (levels 2/3/4)
__global__ void scatter_add_kernel(const float* __restrict__ src,
                                   const int* __restrict__ parent,
                                   float* __restrict__ dst, int nrows) {
    int total = nrows * C;
    int stride = gridDim.x * blockDim.x;
    for (int e = blockIdx.x * blockDim.x + threadIdx.x; e < total; e += stride) {
        unsigned ue = (unsigned)e;
        unsigned r = ue / C;
        unsigned c = ue - r * C;
        atomicAdd(&dst[(unsigned)parent[r] * C + c], src[e]);
    }
}

// ---------------------------------------------------------- counting sort
__global__ void hist_kernel(const int* __restrict__ parent,
                            int* __restrict__ cnt, int n) {
    int i = blockIdx.x * blockDim.x + threadIdx.x;
    int stride = gridDim.x * blockDim.x;
    for (; i < n; i += stride) atomicAdd(&cnt[parent[i]], 1);
}

__global__ void scan_block_kernel(const int* __restrict__ cnt,
                                  int* __restrict__ excl,
                                  int* __restrict__ bsum, int n) {
    __shared__ int lds[256];
    int tid = threadIdx.x;
    int g = blockIdx.x * 256 + tid;
    int v = (g < n) ? cnt[g] : 0;
    lds[tid] = v;
    __syncthreads();
    for (int off = 1; off < 256; off <<= 1) {
        int t = (tid >= off) ? lds[tid - off] : 0;
        __syncthreads();
        lds[tid] += t;
        __syncthreads();
    }
    if (g < n) excl[g] = lds[tid] - v;
    if (tid == 255) bsum[blockIdx.x] = lds[255];
}

__global__ void scan_top_kernel(int* __restrict__ bsum, int nb) {
    __shared__ int lds[512];
    int tid = threadIdx.x;
    int v = (tid < nb) ? bsum[tid] : 0;
    lds[tid] = v;
    __syncthreads();
    for (int off = 1; off < 512; off <<= 1) {
        int t = (tid >= off) ? lds[tid - off] : 0;
        __syncthreads();
        lds[tid] += t;
        __syncthreads();
    }
    if (tid < nb) bsum[tid] = lds[tid] - v;
}

__global__ void scan_fix_kernel(int* __restrict__ excl, const int* __restrict__ bsum,
                                int* __restrict__ cursor, int n) {
    int g = blockIdx.x * 256 + threadIdx.x;
    if (g >= n) return;
    int o = excl[g] + bsum[blockIdx.x];
    excl[g] = o;
    cursor[g] = o;
}

__global__ void reorder_kernel(const int* __restrict__ parent,
                               int* __restrict__ cursor,
                               int* __restrict__ rowid, int n) {
    int i = blockIdx.x * blockDim.x + threadIdx.x;
    int stride = gridDim.x * blockDim.x;
    for (; i < n; i += stride) {
        int r = parent[i];
        int p = atomicAdd(&cursor[r], 1);
        rowid[p] = i;
    }
}

// ---------------------------------------------- gather-style segment sum
// One 64-lane wave per segment; lanes 0..47 own one channel each.
// Rowids for the whole segment prefetched in ONE coalesced load (lane k
// holds rowid[start+k]); broadcast via __shfl. 8 independent predicated
// src-row loads in flight per iteration.
__global__ void segsum_kernel(const float* __restrict__ src,
                              const int* __restrict__ rowid,
                              const int* __restrict__ offs,
                              const int* __restrict__ cnt,
                              float* __restrict__ dst, int nseg) {
    int wid = threadIdx.x >> 6;
    int lane = threadIdx.x & 63;
    int seg = blockIdx.x * (blockDim.x >> 6) + wid;
    if (seg >= nseg) return;
    int start = offs[seg];
    int n = cnt[seg];
    int rv = 0;
    if (lane < n) rv = rowid[start + lane];   // covers n <= 64 in one load
    const bool ch = (lane < C);
    float acc = 0.f;
    int n64 = n < 64 ? n : 64;
    int k = 0;
    for (; k + 8 <= n64; k += 8) {
        float v[8];
#pragma unroll
        for (int j = 0; j < 8; ++j) {
            int r = __shfl(rv, k + j);
            v[j] = ch ? src[(size_t)r * C + lane] : 0.f;
        }
#pragma unroll
        for (int j = 0; j < 8; ++j) acc += v[j];
    }
    float v[4] = {0.f, 0.f, 0.f, 0.f};
    for (int j = 0; k < n64; ++k, ++j) {
        int r = __shfl(rv, k);
        if (ch) v[j & 3] += src[(size_t)r * C + lane];
    }
    acc += (v[0] + v[1]) + (v[2] + v[3]);
    for (; k < n; ++k) {                      // rare: n > 64
        int r = rowid[start + k];
        if (ch) acc += src[(size_t)r * C + lane];
    }
    if (ch) dst[(size_t)seg * C + lane] = acc;
}

// ------------------------------------------------------- per-row argmax
__device__ __forceinline__ int argmax48(const float4* __restrict__ row) {
    float best = -__builtin_inff();
    int bi = 0;
#pragma unroll
    for (int i = 0; i < 12; ++i) {
        float4 v = row[i];
        if (v.x > best) { best = v.x; bi = 4 * i + 0; }
        if (v.y > best) { best = v.y; bi = 4 * i + 1; }
        if (v.z > best) { best = v.z; bi = 4 * i + 2; }
        if (v.w > best) { best = v.w; bi = 4 * i + 3; }
    }
    return bi;
}

__global__ void row_argmax_kernel(const float4* __restrict__ tables,
                                  unsigned char* __restrict__ tab) {
    int r = blockIdx.x * blockDim.x + threadIdx.x;
    if (r >= NROWS) return;
    tab[r] = (unsigned char)argmax48(tables + (unsigned)r * 12u);
}

__global__ void final_gather_kernel(const unsigned char* __restrict__ tab2,
                                    const unsigned char* __restrict__ tab3,
                                    const unsigned char* __restrict__ tab4,
                                    const unsigned char* __restrict__ tab5,
                                    const int* __restrict__ idx2,
                                    const int* __restrict__ idx3,
                                    const int* __restrict__ idx4,
                                    const int* __restrict__ idx5,
                                    int* __restrict__ out) {
    int p = blockIdx.x * blockDim.x + threadIdx.x;
    if (p >= N1) return;
    out[0 * N1 + p] = (int)tab2[idx2[p]];
    out[1 * N1 + p] = (int)tab3[idx3[p]];
    out[2 * N1 + p] = (int)tab4[idx4[p]];
    out[3 * N1 + p] = (int)tab5[idx5[p]];
}

extern "C" void kernel_launch(void* const* d_in, const int* in_sizes, int n_in,
                              void* d_out, int out_size, void* d_ws, size_t ws_size,
                              hipStream_t stream) {
    const float* slabel  = (const float*)d_in[0];
    const int* parent2   = (const int*)d_in[1];
    const int* parent3   = (const int*)d_in[2];
    const int* parent4   = (const int*)d_in[3];
    const int* parent5   = (const int*)d_in[4];
    const int* idx2      = (const int*)d_in[5];
    const int* idx3      = (const int*)d_in[6];
    const int* idx4      = (const int*)d_in[7];
    const int* idx5      = (const int*)d_in[8];
    int* out = (int*)d_out;   // JAX argmax output dtype is int32

    // ---- workspace layout (dwords) ----
    // zeroed: [f2|f3|f4|f5|tab|cnt2]   unzeroed: [offs2|cur2|rowid2|bsum]
    float* f2 = (float*)d_ws;
    float* f3 = f2 + (size_t)N2 * C;
    float* f4 = f3 + (size_t)N3 * C;
    float* f5 = f4 + (size_t)N4 * C;
    unsigned char* tab = (unsigned char*)(f5 + (size_t)N5 * C);
    unsigned char* tab2 = tab;
    unsigned char* tab3 = tab2 + N2;
    unsigned char* tab4 = tab3 + N3;
    unsigned char* tab5 = tab4 + N4;
    int* cnt2   = (int*)(tab + NROWS);     // NROWS bytes = 37,376 dwords
    int* offs2  = cnt2 + N2;               // end of zeroed region
    int* cur2   = offs2 + N2;
    int* rowid2 = cur2 + N2;
    int* bsum   = rowid2 + N1;             // 512 ints

    const int zero_dwords = NROWS * C + NROWS / 4 + N2;  // 7,344,640
    const int zero_f4 = zero_dwords / 4;

    const int BLK = 256;

    // 1) zero accumulators + histogram (ws is poisoned between calls)
    zero_kernel<<<2048, BLK, 0, stream>>>((float4*)d_ws, zero_f4);

    // 2) level 1: counting-sort + ILP-8 gather segment-sum (slabel -> f2)
    hist_kernel<<<2048, BLK, 0, stream>>>(parent2, cnt2, N1);
    scan_block_kernel<<<N2 / 256, 256, 0, stream>>>(cnt2, offs2, bsum, N2);
    scan_top_kernel<<<1, 512, 0, stream>>>(bsum, N2 / 256);
    scan_fix_kernel<<<N2 / 256, 256, 0, stream>>>(offs2, bsum, cur2, N2);
    reorder_kernel<<<2048, BLK, 0, stream>>>(parent2, cur2, rowid2, N1);
    segsum_kernel<<<N2 / 4, BLK, 0, stream>>>(slabel, rowid2, offs2, cnt2, f2, N2);

    // 3) levels 2/3/4: plain atomics (f2 -> f3 -> f4 -> f5)
    scatter_add_kernel<<<2048, BLK, 0, stream>>>(f2, parent3, f3, N2);
    scatter_add_kernel<<<512,  BLK, 0, stream>>>(f3, parent4, f4, N3);
    scatter_add_kernel<<<128,  BLK, 0, stream>>>(f4, parent5, f5, N4);

    // 4) per-row argmax over all four tables (contiguous)
    row_argmax_kernel<<<(NROWS + BLK - 1) / BLK, BLK, 0, stream>>>(
        (const float4*)d_ws, tab);

    // 5) per-point gather of precomputed argmax
    final_gather_kernel<<<(N1 + BLK - 1) / BLK, BLK, 0, stream>>>(
        tab2, tab3, tab4, tab5, idx2, idx3, idx4, idx5, out);
}

// Round 6
// 235.495 us; speedup vs baseline: 1.2419x; 1.0494x over previous
//
#include <hip/hip_runtime.h>

#define N1 1000000
#define N2 131072
#define N3 16384
#define N4 2048
#define N5 256
#define C 48

// ---------------------------------------------------------------- zero ws
__global__ void zero_kernel(float4* __restrict__ p, int n4) {
    int i = blockIdx.x * blockDim.x + threadIdx.x;
    if (i < n4) p[i] = make_float4(0.f, 0.f, 0.f, 0.f);
}

// ------------------------------------------------------------- histogram
__global__ void hist_kernel(const int4* __restrict__ parent,
                            int* __restrict__ cnt, int nq) {
    int i = blockIdx.x * blockDim.x + threadIdx.x;
    if (i >= nq) return;
    int4 p = parent[i];
    atomicAdd(&cnt[p.x], 1);
    atomicAdd(&cnt[p.y], 1);
    atomicAdd(&cnt[p.z], 1);
    atomicAdd(&cnt[p.w], 1);
}

// ------------------------------------- per-256-chunk exclusive scan + sums
__global__ void scan_block_kernel(const int* __restrict__ cnt,
                                  int* __restrict__ excl,
                                  int* __restrict__ bsum, int n) {
    __shared__ int lds[256];
    int tid = threadIdx.x;
    int g = blockIdx.x * 256 + tid;
    int v = (g < n) ? cnt[g] : 0;
    lds[tid] = v;
    __syncthreads();
    for (int off = 1; off < 256; off <<= 1) {
        int t = (tid >= off) ? lds[tid - off] : 0;
        __syncthreads();
        lds[tid] += t;
        __syncthreads();
    }
    if (g < n) excl[g] = lds[tid] - v;
    if (tid == 255) bsum[blockIdx.x] = lds[255];
}

// ---- add chunk-prefix (computed inline from bsum) -> final offs + cursor
__global__ void scan_fix_kernel(int* __restrict__ excl,
                                const int* __restrict__ bsum,
                                int* __restrict__ cursor, int n) {
    __shared__ int red[256];
    int b = blockIdx.x;     // 512 blocks of 256
    int tid = threadIdx.x;
    int v0 = (tid < b) ? bsum[tid] : 0;
    int v1 = (tid + 256 < b) ? bsum[tid + 256] : 0;
    red[tid] = v0 + v1;
    __syncthreads();
    for (int off = 128; off > 0; off >>= 1) {
        if (tid < off) red[tid] += red[tid + off];
        __syncthreads();
    }
    int top = red[0];
    int g = b * 256 + tid;
    if (g < n) {
        int o = excl[g] + top;
        excl[g] = o;
        cursor[g] = o;
    }
}

__global__ void reorder_kernel(const int* __restrict__ parent,
                               int* __restrict__ cursor,
                               int* __restrict__ rowid, int n) {
    int i = blockIdx.x * blockDim.x + threadIdx.x;
    int stride = gridDim.x * blockDim.x;
    for (; i < n; i += stride) {
        int r = parent[i];
        int p = atomicAdd(&cursor[r], 1);
        rowid[p] = i;
    }
}

// --------------------- fused: segment-sum + row-argmax + f3 accumulation
// One 64-lane wave per segment; lanes 0..47 own one channel each.
// f2 row lives only in registers: argmax -> tab2, atomicAdd -> f3.
__global__ void segsum_fused_kernel(const float* __restrict__ src,
                                    const int* __restrict__ rowid,
                                    const int* __restrict__ offs,
                                    const int* __restrict__ cnt,
                                    const int* __restrict__ parent3,
                                    float* __restrict__ f3,
                                    unsigned char* __restrict__ tab2, int nseg) {
    int wid = threadIdx.x >> 6;
    int lane = threadIdx.x & 63;
    int seg = blockIdx.x * (blockDim.x >> 6) + wid;
    if (seg >= nseg) return;
    int start = offs[seg];
    int n = cnt[seg];
    int rv = (lane < n) ? rowid[start + lane] : 0;   // n <= 64 in one load
    const bool ch = (lane < C);
    float acc = 0.f;
    int n64 = n < 64 ? n : 64;
    int k = 0;
    for (; k + 8 <= n64; k += 8) {
        float v[8];
#pragma unroll
        for (int j = 0; j < 8; ++j) {
            int r = __shfl(rv, k + j);
            v[j] = ch ? src[(size_t)r * C + lane] : 0.f;
        }
#pragma unroll
        for (int j = 0; j < 8; ++j) acc += v[j];
    }
    {
        float v[4] = {0.f, 0.f, 0.f, 0.f};
        for (int j = 0; k < n64; ++k, ++j) {
            int r = __shfl(rv, k);
            if (ch) v[j & 3] += src[(size_t)r * C + lane];
        }
        acc += (v[0] + v[1]) + (v[2] + v[3]);
    }
    for (; k < n; ++k) {                  // rare: n > 64
        int r = rowid[start + k];
        if (ch) acc += src[(size_t)r * C + lane];
    }
    // ---- accumulate this f2 row into f3 (replaces scatter2 kernel)
    int p3 = parent3[seg];
    if (ch) atomicAdd(&f3[(size_t)p3 * C + lane], acc);
    // ---- wave argmax of the f2 row (first-max tie-break: smaller index)
    float bv = ch ? acc : -__builtin_inff();
    int bi = ch ? lane : 0x7fffffff;
#pragma unroll
    for (int d = 32; d > 0; d >>= 1) {
        float ov = __shfl_xor(bv, d);
        int oi = __shfl_xor(bi, d);
        if (ov > bv || (ov == bv && oi < bi)) { bv = ov; bi = oi; }
    }
    if (lane == 0) tab2[seg] = (unsigned char)bi;
}

// ------------------------------------------------------- per-row argmax
__device__ __forceinline__ int argmax48(const float4* __restrict__ row) {
    float best = -__builtin_inff();
    int bi = 0;
#pragma unroll
    for (int i = 0; i < 12; ++i) {
        float4 v = row[i];
        if (v.x > best) { best = v.x; bi = 4 * i + 0; }
        if (v.y > best) { best = v.y; bi = 4 * i + 1; }
        if (v.z > best) { best = v.z; bi = 4 * i + 2; }
        if (v.w > best) { best = v.w; bi = 4 * i + 3; }
    }
    return bi;
}

// ----------- fused level kernel: atomic scatter (blocks < nblkA) + row argmax
__global__ void level_kernel(const float* __restrict__ fsrc,
                             const int* __restrict__ parent,
                             float* __restrict__ fdst,
                             unsigned char* __restrict__ tabsrc,
                             int nrows, int nblkA) {
    if ((int)blockIdx.x < nblkA) {
        int e = blockIdx.x * 256 + threadIdx.x;
        if (e < nrows * C) {
            unsigned r = (unsigned)e / C;
            unsigned c = (unsigned)e - r * C;
            atomicAdd(&fdst[(unsigned)parent[r] * C + c], fsrc[e]);
        }
    } else {
        int r = (blockIdx.x - nblkA) * 256 + threadIdx.x;
        if (r < nrows) tabsrc[r] = (unsigned char)argmax48((const float4*)fsrc + r * 12);
    }
}

// --------------- final gather: tab2/3/4 lookups + direct f5 argmax (48 KB)
__global__ void final_kernel(const unsigned char* __restrict__ tab2,
                             const unsigned char* __restrict__ tab3,
                             const unsigned char* __restrict__ tab4,
                             const float4* __restrict__ f5,
                             const int4* __restrict__ idx2,
                             const int4* __restrict__ idx3,
                             const int4* __restrict__ idx4,
                             const int4* __restrict__ idx5,
                             int4* __restrict__ out) {
    const int NQ = N1 / 4;
    int t = blockIdx.x * blockDim.x + threadIdx.x;
    if (t >= NQ) return;
    int4 a = idx2[t], b = idx3[t], c = idx4[t], d = idx5[t];
    out[t] = make_int4(tab2[a.x], tab2[a.y], tab2[a.z], tab2[a.w]);
    out[NQ + t] = make_int4(tab3[b.x], tab3[b.y], tab3[b.z], tab3[b.w]);
    out[2 * NQ + t] = make_int4(tab4[c.x], tab4[c.y], tab4[c.z], tab4[c.w]);
    out[3 * NQ + t] = make_int4(argmax48(f5 + (unsigned)d.x * 12u),
                                argmax48(f5 + (unsigned)d.y * 12u),
                                argmax48(f5 + (unsigned)d.z * 12u),
                                argmax48(f5 + (unsigned)d.w * 12u));
}

extern "C" void kernel_launch(void* const* d_in, const int* in_sizes, int n_in,
                              void* d_out, int out_size, void* d_ws, size_t ws_size,
                              hipStream_t stream) {
    const float* slabel  = (const float*)d_in[0];
    const int* parent2   = (const int*)d_in[1];
    const int* parent3   = (const int*)d_in[2];
    const int* parent4   = (const int*)d_in[3];
    const int* parent5   = (const int*)d_in[4];
    const int* idx2      = (const int*)d_in[5];
    const int* idx3      = (const int*)d_in[6];
    const int* idx4      = (const int*)d_in[7];
    const int* idx5      = (const int*)d_in[8];
    int* out = (int*)d_out;   // JAX argmax output dtype is int32

    // ---- workspace layout (dwords) ----
    // zeroed: [f3 | f4 | f5 | cnt2]      (f2 never materializes)
    // unzeroed: [offs2 | cur2 | rowid2 | bsum | tab2 | tab3 | tab4 (bytes)]
    float* f3 = (float*)d_ws;
    float* f4 = f3 + (size_t)N3 * C;
    float* f5 = f4 + (size_t)N4 * C;
    int* cnt2 = (int*)(f5 + (size_t)N5 * C);
    int* offs2 = cnt2 + N2;                 // end of zeroed region
    int* cur2 = offs2 + N2;
    int* rowid2 = cur2 + N2;
    int* bsum = rowid2 + N1;                // 512 ints
    unsigned char* tab2 = (unsigned char*)(bsum + 512);
    unsigned char* tab3 = tab2 + N2;
    unsigned char* tab4 = tab3 + N3;

    const int zero_dwords = (N3 + N4 + N5) * C + N2;   // 1,028,096
    const int zero_f4 = zero_dwords / 4;               // 257,024 -> 1004 blocks

    // 1) zero f3/f4/f5 + histogram (ws poisoned between calls)
    zero_kernel<<<zero_f4 / 256, 256, 0, stream>>>((float4*)d_ws, zero_f4);

    // 2) counting sort of level-1 rows by parent2
    hist_kernel<<<(N1 / 4 + 255) / 256, 256, 0, stream>>>((const int4*)parent2, cnt2, N1 / 4);
    scan_block_kernel<<<N2 / 256, 256, 0, stream>>>(cnt2, offs2, bsum, N2);
    scan_fix_kernel<<<N2 / 256, 256, 0, stream>>>(offs2, bsum, cur2, N2);
    reorder_kernel<<<2048, 256, 0, stream>>>(parent2, cur2, rowid2, N1);

    // 3) fused: segment-sum (f2 in registers) + argmax->tab2 + atomic f3
    segsum_fused_kernel<<<N2 / 4, 256, 0, stream>>>(
        slabel, rowid2, offs2, cnt2, parent3, f3, tab2, N2);

    // 4) level 3: f3->f4 atomics (3072 blocks) + tab3 argmax (64 blocks)
    level_kernel<<<3072 + 64, 256, 0, stream>>>(f3, parent4, f4, tab3, N3, 3072);

    // 5) level 4: f4->f5 atomics (384 blocks) + tab4 argmax (8 blocks)
    level_kernel<<<384 + 8, 256, 0, stream>>>(f4, parent5, f5, tab4, N4, 384);

    // 6) final: tab lookups + direct argmax of L1-resident f5
    final_kernel<<<(N1 / 4 + 255) / 256, 256, 0, stream>>>(
        tab2, tab3, tab4, (const float4*)f5,
        (const int4*)idx2, (const int4*)idx3, (const int4*)idx4, (const int4*)idx5,
        (int4*)out);
}